// Round 3
// baseline (664.508 us; speedup 1.0000x reference)
//
#include <hip/hip_runtime.h>

#define MIN_NORM 1e-15f
#define MAXN (1.0f - 4e-3f)

__device__ __forceinline__ float bf2f(unsigned short u) {
  union { unsigned int i; float f; } c; c.i = ((unsigned int)u) << 16; return c.f;
}
__device__ __forceinline__ unsigned short f2bf(float f) {
  union { float f; unsigned int i; } c; c.f = f;
  unsigned int r = c.i + 0x7FFFu + ((c.i >> 16) & 1u);
  return (unsigned short)(r >> 16);
}
__device__ __forceinline__ float wave_sum(float v) {
#pragma unroll
  for (int off = 32; off > 0; off >>= 1) v += __shfl_xor(v, off, 64);
  return v;
}

// ---------------- hb = proj(expmap0(b_lin)), plus |hb|^2 (fp32 in) ----------------
__global__ void k_hb(const float* __restrict__ b_lin,
                     float* __restrict__ hb, float* __restrict__ hb2) {
  int lane = threadIdx.x;  // 64 threads, 4 floats each = 256
  float4 u = ((const float4*)b_lin)[lane];
  float bx = u.x, by = u.y, bz = u.z, bw = u.w;
  float s = wave_sum(bx * bx + by * by + bz * bz + bw * bw);
  float n1 = fmaxf(sqrtf(s), MIN_NORM);
  float t = tanhf(n1) / n1;
  bx *= t; by *= t; bz *= t; bw *= t;
  float s2 = wave_sum(bx * bx + by * by + bz * bz + bw * bw);
  float n2 = fmaxf(sqrtf(s2), MIN_NORM);
  if (n2 > MAXN) { float f = MAXN / n2; bx *= f; by *= f; bz *= f; bw *= f; }
  float4 o; o.x = bx; o.y = by; o.z = bz; o.w = bw;
  ((float4*)hb)[lane] = o;
  float s3 = wave_sum(bx * bx + by * by + bz * bz + bw * bw);
  if (lane == 0) *hb2 = s3;
}

// ---------------- per-row logmap0 scale: rs[i] = atanh(min(|x_i|,1-1e-7))/|x_i| ----
__global__ __launch_bounds__(256) void k_rownorm(const float* __restrict__ x,
                                                 float* __restrict__ rs, int N) {
  int row = blockIdx.x * 4 + (threadIdx.x >> 6);
  int lane = threadIdx.x & 63;
  float4 u = *(const float4*)(x + (size_t)row * 256 + lane * 4);
  float s = wave_sum(u.x * u.x + u.y * u.y + u.z * u.z + u.w * u.w);
  if (lane == 0) {
    float n = fmaxf(sqrtf(s), MIN_NORM);
    rs[row] = atanhf(fminf(n, 1.0f - 1e-7f)) / n;
  }
}

// ---------------- GEMM: V[i,j] = rs[i] * sum_k x[i,k]*W[j,k]  (fp32 in, fp32 out) --
#define GBM 64
#define GBN 64
#define GBK 16
__global__ __launch_bounds__(256) void k_gemm(const float* __restrict__ A,
                                              const float* __restrict__ B,
                                              const float* __restrict__ rs,
                                              float* __restrict__ C, int M) {
  __shared__ __align__(16) float As[GBK][GBM + 4];
  __shared__ __align__(16) float Bs[GBK][GBN + 4];
  int i0 = blockIdx.x * GBM;
  int j0 = blockIdx.y * GBN;
  int tid = threadIdx.x;
  int lrow = tid >> 2, lc = (tid & 3) * 4;  // each thread loads 4 floats (float4)
  int ty = tid >> 4, tx = tid & 15;
  float acc[4][4] = {};
  for (int k0 = 0; k0 < 256; k0 += GBK) {
    int ar = i0 + lrow;
    float4 ua;
    if (ar < M) ua = *(const float4*)(A + (size_t)ar * 256 + k0 + lc);
    else { ua.x = ua.y = ua.z = ua.w = 0.0f; }
    As[lc + 0][lrow] = ua.x;
    As[lc + 1][lrow] = ua.y;
    As[lc + 2][lrow] = ua.z;
    As[lc + 3][lrow] = ua.w;
    float4 ub = *(const float4*)(B + (size_t)(j0 + lrow) * 256 + k0 + lc);
    Bs[lc + 0][lrow] = ub.x;
    Bs[lc + 1][lrow] = ub.y;
    Bs[lc + 2][lrow] = ub.z;
    Bs[lc + 3][lrow] = ub.w;
    __syncthreads();
#pragma unroll
    for (int kk = 0; kk < GBK; ++kk) {
      float4 a4 = *(const float4*)&As[kk][ty * 4];
      float4 b4 = *(const float4*)&Bs[kk][tx * 4];
      float av[4] = {a4.x, a4.y, a4.z, a4.w};
      float bv[4] = {b4.x, b4.y, b4.z, b4.w};
#pragma unroll
      for (int ii = 0; ii < 4; ++ii)
#pragma unroll
        for (int jj = 0; jj < 4; ++jj)
          acc[ii][jj] = fmaf(av[ii], bv[jj], acc[ii][jj]);
    }
    __syncthreads();
  }
#pragma unroll
  for (int ii = 0; ii < 4; ++ii) {
    int r = i0 + ty * 4 + ii;
    if (r < M) {
      float sc = rs[r];
      float4 st;
      st.x = sc * acc[ii][0];
      st.y = sc * acc[ii][1];
      st.z = sc * acc[ii][2];
      st.w = sc * acc[ii][3];
      *(float4*)(C + (size_t)r * 256 + j0 + tx * 4) = st;
    }
  }
}

// ---------------- hyperbolic chain per row: V -> L = logmap0(proj(mobius(proj(expmap0(V)),hb)))
__global__ __launch_bounds__(256) void k_hyp(const float* __restrict__ V,
                                             const float* __restrict__ hb,
                                             const float* __restrict__ hb2p,
                                             unsigned short* __restrict__ L) {
  int row = blockIdx.x * 4 + (threadIdx.x >> 6);
  int lane = threadIdx.x & 63;
  float4 u = *(const float4*)(V + (size_t)row * 256 + lane * 4);
  float vx = u.x, vy = u.y, vz = u.z, vw = u.w;
  float4 h4 = ((const float4*)hb)[lane];
  float y2 = *hb2p;
  // expmap0
  float s1 = wave_sum(vx * vx + vy * vy + vz * vz + vw * vw);
  float n1 = fmaxf(sqrtf(s1), MIN_NORM);
  float e1 = tanhf(n1) / n1;
  vx *= e1; vy *= e1; vz *= e1; vw *= e1;
  // proj
  float s2 = wave_sum(vx * vx + vy * vy + vz * vz + vw * vw);
  float n2 = fmaxf(sqrtf(s2), MIN_NORM);
  if (n2 > MAXN) { float f = MAXN / n2; vx *= f; vy *= f; vz *= f; vw *= f; }
  // mobius_add(v, hb)
  float x2 = wave_sum(vx * vx + vy * vy + vz * vz + vw * vw);
  float xy = wave_sum(vx * h4.x + vy * h4.y + vz * h4.z + vw * h4.w);
  float c1 = 1.0f + 2.0f * xy + y2;
  float c2 = 1.0f - x2;
  float den = fmaxf(1.0f + 2.0f * xy + x2 * y2, MIN_NORM);
  float inv = 1.0f / den;
  float zx = (c1 * vx + c2 * h4.x) * inv;
  float zy = (c1 * vy + c2 * h4.y) * inv;
  float zz = (c1 * vz + c2 * h4.z) * inv;
  float zw = (c1 * vw + c2 * h4.w) * inv;
  // proj
  float s3 = wave_sum(zx * zx + zy * zy + zz * zz + zw * zw);
  float n3 = fmaxf(sqrtf(s3), MIN_NORM);
  if (n3 > MAXN) { float f = MAXN / n3; zx *= f; zy *= f; zz *= f; zw *= f; }
  // logmap0
  float s4 = wave_sum(zx * zx + zy * zy + zz * zz + zw * zw);
  float n4 = fmaxf(sqrtf(s4), MIN_NORM);
  float sc = atanhf(fminf(n4, 1.0f - 1e-7f)) / n4;
  ushort4 st;
  st.x = f2bf(sc * zx);
  st.y = f2bf(sc * zy);
  st.z = f2bf(sc * zz);
  st.w = f2bf(sc * zw);
  *(ushort4*)(L + (size_t)row * 256 + lane * 4) = st;
}

// ---------------- attention partial scores s_i[n*4+h], s_j[n*4+h] ----------------
__global__ __launch_bounds__(256) void k_satt(const unsigned short* __restrict__ L,
                                              const float* __restrict__ att,
                                              float* __restrict__ s_i,
                                              float* __restrict__ s_j, int N) {
  int n = blockIdx.x;
  int h = threadIdx.x >> 6;
  int lane = threadIdx.x & 63;
  float f = bf2f(L[(size_t)h * N * 64 + (size_t)n * 64 + lane]);
  float wi = att[h * 128 + lane];
  float wj = att[h * 128 + 64 + lane];
  float si = wave_sum(f * wi);
  float sj = wave_sum(f * wj);
  if (lane == 0) {
    s_i[n * 4 + h] = si;
    s_j[n * 4 + h] = sj;
  }
}

// ---------------- CSR buckets: self-loop in slot 0, edges appended ----------------
__global__ void k_init(int* __restrict__ cnt, int* __restrict__ slots, int N) {
  int n = blockIdx.x * blockDim.x + threadIdx.x;
  if (n < N) { cnt[n] = 1; slots[n * 64] = n; }
}
__global__ void k_fill(const int* __restrict__ ei, int* __restrict__ cnt,
                       int* __restrict__ slots, int E) {
  int e = blockIdx.x * blockDim.x + threadIdx.x;
  if (e < E) {
    int s = ei[e];
    int d = ei[E + e];
    int pos = atomicAdd(&cnt[d], 1);
    if (pos < 64) slots[d * 64 + pos] = s;
  }
}

// ---------------- aggregation + epilogue per FINAL row i -------------------------
// row i: h = i/(N/4), q = i%(N/4); warp r handles node n=4q+r, cols 64r..64r+63
__global__ __launch_bounds__(256) void HGATLayer_49246095016355_kernel(
    const unsigned short* __restrict__ L,
    const float* __restrict__ s_i,
    const float* __restrict__ s_j,
    const int* __restrict__ cnt,
    const int* __restrict__ slots,
    const float* __restrict__ b_conv,
    float* __restrict__ out, int N) {
  int i = blockIdx.x;
  int NQ = N >> 2;
  int h = i / NQ;
  int q = i - h * NQ;
  int warp = threadIdx.x >> 6, lane = threadIdx.x & 63;
  int n = q * 4 + warp;
  float si = s_i[n * 4 + h];
  int deg = min(cnt[n], 64);
  const int* sl = slots + (size_t)n * 64;
  const unsigned short* Lh = L + (size_t)h * N * 64;
  float m = -1e30f, l = 0.0f, acc = 0.0f;
  for (int k = 0; k < deg; ++k) {
    int src = sl[k];
    float a = si + s_j[src * 4 + h];
    a = (a > 0.0f) ? a : 0.2f * a;  // leaky_relu 0.2
    float f = bf2f(Lh[(size_t)src * 64 + lane]);
    float mn = fmaxf(m, a);
    float scl = __expf(m - mn);
    float p = __expf(a - mn);
    acc = acc * scl + p * f;
    l = l * scl + p;
    m = mn;
  }
  float val = acc / fmaxf(l, MIN_NORM);
  val += b_conv[threadIdx.x];
  val = fmaxf(val, 0.0f);  // relu
  // block-wide sumsq over 256 cols of this final row
  float ps = wave_sum(val * val);
  __shared__ float red[4];
  if (lane == 0) red[warp] = ps;
  __syncthreads();
  float tot = red[0] + red[1] + red[2] + red[3];
  float nraw = sqrtf(tot);
  float nc = fmaxf(nraw, MIN_NORM);
  float t = tanhf(nc) / nc;  // expmap0 scale
  float y = t * val;
  float ny = fmaxf(t * nraw, MIN_NORM);  // = |y|
  if (ny > MAXN) y *= MAXN / ny;         // proj
  out[(size_t)i * 256 + threadIdx.x] = y;
}

extern "C" void kernel_launch(void* const* d_in, const int* in_sizes, int n_in,
                              void* d_out, int out_size, void* d_ws, size_t ws_size,
                              hipStream_t stream) {
  const float* x   = (const float*)d_in[0];
  const int*   ei  = (const int*)d_in[1];
  const float* W   = (const float*)d_in[2];
  const float* bl  = (const float*)d_in[3];
  const float* att = (const float*)d_in[4];
  const float* bc  = (const float*)d_in[5];
  float* out = (float*)d_out;

  const int N = in_sizes[0] / 256;  // 50000
  const int E = in_sizes[1] / 2;    // 800000

  char* w = (char*)d_ws;
  unsigned short* L = (unsigned short*)w; w += (size_t)N * 256 * 2;  // 25.6 MB bf16
  float* s_i = (float*)w; w += (size_t)N * 4 * 4;
  float* s_j = (float*)w; w += (size_t)N * 4 * 4;
  float* rs  = (float*)w; w += (size_t)N * 4;
  float* hb  = (float*)w; w += 256 * 4;
  float* hb2 = (float*)w; w += 16;
  int* cnt   = (int*)w;   w += (size_t)N * 4;
  int* slots = (int*)w;   // N*64 ints = 12.8 MB

  k_hb<<<1, 64, 0, stream>>>(bl, hb, hb2);
  k_rownorm<<<N / 4, 256, 0, stream>>>(x, rs, N);
  // V (fp32) staged in d_out (12.8M floats), consumed by k_hyp, then overwritten
  k_gemm<<<dim3((N + 63) / 64, 4), 256, 0, stream>>>(x, W, rs, (float*)d_out, N);
  k_hyp<<<N / 4, 256, 0, stream>>>((const float*)d_out, hb, hb2, L);
  k_satt<<<N, 256, 0, stream>>>(L, att, s_i, s_j, N);
  k_init<<<(N + 255) / 256, 256, 0, stream>>>(cnt, slots, N);
  k_fill<<<(E + 255) / 256, 256, 0, stream>>>(ei, cnt, slots, E);
  HGATLayer_49246095016355_kernel<<<N, 256, 0, stream>>>(L, s_i, s_j, cnt, slots, bc, out, N);
}

// Round 4
// 385.639 us; speedup vs baseline: 1.7231x; 1.7231x over previous
//
#include <hip/hip_runtime.h>

#define MIN_NORM 1e-15f
#define MAXN (1.0f - 4e-3f)

typedef __attribute__((ext_vector_type(8))) short short8;   // 8 bf16 (4 VGPRs)
typedef __attribute__((ext_vector_type(4))) float f32x4;    // 4 fp32 acc

__device__ __forceinline__ float bf2f(unsigned short u) {
  union { unsigned int i; float f; } c; c.i = ((unsigned int)u) << 16; return c.f;
}
__device__ __forceinline__ unsigned short f2bf(float f) {
  union { float f; unsigned int i; } c; c.f = f;
  unsigned int r = c.i + 0x7FFFu + ((c.i >> 16) & 1u);
  return (unsigned short)(r >> 16);
}
__device__ __forceinline__ float wave_sum(float v) {
#pragma unroll
  for (int off = 32; off > 0; off >>= 1) v += __shfl_xor(v, off, 64);
  return v;
}
__device__ __forceinline__ float wave_max(float v) {
#pragma unroll
  for (int off = 32; off > 0; off >>= 1) v = fmaxf(v, __shfl_xor(v, off, 64));
  return v;
}

// ---------------- hb = proj(expmap0(b_lin)), plus |hb|^2 ----------------
__global__ void k_hb(const float* __restrict__ b_lin,
                     float* __restrict__ hb, float* __restrict__ hb2) {
  int lane = threadIdx.x;  // 64 threads x 4 floats = 256
  float4 u = ((const float4*)b_lin)[lane];
  float bx = u.x, by = u.y, bz = u.z, bw = u.w;
  float s = wave_sum(bx * bx + by * by + bz * bz + bw * bw);
  float n1 = fmaxf(sqrtf(s), MIN_NORM);
  float t = tanhf(n1) / n1;
  bx *= t; by *= t; bz *= t; bw *= t;
  float s2 = wave_sum(bx * bx + by * by + bz * bz + bw * bw);
  float n2 = fmaxf(sqrtf(s2), MIN_NORM);
  if (n2 > MAXN) { float f = MAXN / n2; bx *= f; by *= f; bz *= f; bw *= f; }
  float4 o; o.x = bx; o.y = by; o.z = bz; o.w = bw;
  ((float4*)hb)[lane] = o;
  float s3 = wave_sum(bx * bx + by * by + bz * bz + bw * bw);
  if (lane == 0) *hb2 = s3;
}

// ---------------- prep: row-norm scale rs[i] + bf16 cast of x ----------------
__global__ __launch_bounds__(256) void k_prep(const float* __restrict__ x,
                                              float* __restrict__ rs,
                                              unsigned short* __restrict__ xb, int N) {
  int row = blockIdx.x * 4 + (threadIdx.x >> 6);
  int lane = threadIdx.x & 63;
  float4 u = *(const float4*)(x + (size_t)row * 256 + lane * 4);
  ushort4 st;
  st.x = f2bf(u.x); st.y = f2bf(u.y); st.z = f2bf(u.z); st.w = f2bf(u.w);
  *(ushort4*)(xb + (size_t)row * 256 + lane * 4) = st;
  float s = wave_sum(u.x * u.x + u.y * u.y + u.z * u.z + u.w * u.w);
  if (lane == 0) {
    float n = fmaxf(sqrtf(s), MIN_NORM);
    rs[row] = atanhf(fminf(n, 1.0f - 1e-7f)) / n;
  }
}

// ---------------- W (fp32 256x256) -> bf16 ----------------
__global__ __launch_bounds__(256) void k_wb(const float* __restrict__ W,
                                            unsigned short* __restrict__ Wb) {
  int idx = (blockIdx.x * 256 + threadIdx.x) * 4;
  float4 u = *(const float4*)(W + idx);
  ushort4 st;
  st.x = f2bf(u.x); st.y = f2bf(u.y); st.z = f2bf(u.z); st.w = f2bf(u.w);
  *(ushort4*)(Wb + idx) = st;
}

// ---------------- MFMA GEMM: V[i,j] = rs[i] * sum_k x[i,k]*W[j,k] ----------------
// block: 256 thr (4 waves), 64 rows x 64 cols; W col-slice [64][256] staged in LDS.
__global__ __launch_bounds__(256) void k_gemm(const unsigned short* __restrict__ xb,
                                              const unsigned short* __restrict__ Wb,
                                              const float* __restrict__ rs,
                                              float* __restrict__ C, int M) {
  __shared__ unsigned short Ws[64][264];  // +8 pad: 2-way bank alias (free)
  int i0 = blockIdx.x * 64;
  int j0 = blockIdx.y * 64;
  int tid = threadIdx.x;
  // stage W slice: 64 rows x 256 cols bf16 = 32 KB, 8 x (256 thr x 16B)
#pragma unroll
  for (int it = 0; it < 8; ++it) {
    int idx = it * 256 + tid;         // ushort8 index
    int row = idx >> 5;               // /32 (256 cols / 8)
    int col = (idx & 31) * 8;
    *(uint4*)&Ws[row][col] = *(const uint4*)(Wb + (size_t)(j0 + row) * 256 + col);
  }
  __syncthreads();

  int wv = tid >> 6, lane = tid & 63;
  int qd = lane >> 4, lc = lane & 15;
  int arow = i0 + wv * 16 + lc;
  if (arow >= M) arow = M - 1;  // clamp (stores guarded)
  f32x4 acc[4] = {{0.f,0.f,0.f,0.f},{0.f,0.f,0.f,0.f},{0.f,0.f,0.f,0.f},{0.f,0.f,0.f,0.f}};
#pragma unroll
  for (int kk = 0; kk < 8; ++kk) {
    int kb = kk * 32 + qd * 8;
    short8 af = *(const short8*)(xb + (size_t)arow * 256 + kb);
#pragma unroll
    for (int jt = 0; jt < 4; ++jt) {
      short8 bf = *(const short8*)&Ws[jt * 16 + lc][kb];
      acc[jt] = __builtin_amdgcn_mfma_f32_16x16x32_bf16(af, bf, acc[jt], 0, 0, 0);
    }
  }
  // epilogue: row = i0 + wv*16 + qd*4 + r, col = j0 + jt*16 + lc
  float rsv[4];
  int rowb = i0 + wv * 16 + qd * 4;
#pragma unroll
  for (int r = 0; r < 4; ++r) rsv[r] = (rowb + r < M) ? rs[rowb + r] : 0.0f;
#pragma unroll
  for (int jt = 0; jt < 4; ++jt) {
#pragma unroll
    for (int r = 0; r < 4; ++r) {
      int row = rowb + r;
      if (row < M) C[(size_t)row * 256 + j0 + jt * 16 + lc] = rsv[r] * acc[jt][r];
    }
  }
}

// ---------------- hyperbolic chain + fused attention partials ----------------
// V -> L = logmap0(proj(mobius(proj(expmap0(V)),hb))); s_i/s_j = L . att
__global__ __launch_bounds__(256) void k_hyp(const float* __restrict__ V,
                                             const float* __restrict__ hb,
                                             const float* __restrict__ hb2p,
                                             const float* __restrict__ att,
                                             unsigned short* __restrict__ L,
                                             float* __restrict__ s_i,
                                             float* __restrict__ s_j) {
  int row = blockIdx.x * 4 + (threadIdx.x >> 6);
  int lane = threadIdx.x & 63;
  float4 u = *(const float4*)(V + (size_t)row * 256 + lane * 4);
  float vx = u.x, vy = u.y, vz = u.z, vw = u.w;
  float4 h4 = ((const float4*)hb)[lane];
  float y2 = *hb2p;
  // expmap0
  float s1 = wave_sum(vx * vx + vy * vy + vz * vz + vw * vw);
  float n1 = fmaxf(sqrtf(s1), MIN_NORM);
  float e1 = tanhf(n1) / n1;
  vx *= e1; vy *= e1; vz *= e1; vw *= e1;
  // proj
  float s2 = wave_sum(vx * vx + vy * vy + vz * vz + vw * vw);
  float n2 = fmaxf(sqrtf(s2), MIN_NORM);
  if (n2 > MAXN) { float f = MAXN / n2; vx *= f; vy *= f; vz *= f; vw *= f; }
  // mobius_add(v, hb)
  float x2 = wave_sum(vx * vx + vy * vy + vz * vz + vw * vw);
  float xy = wave_sum(vx * h4.x + vy * h4.y + vz * h4.z + vw * h4.w);
  float c1 = 1.0f + 2.0f * xy + y2;
  float c2 = 1.0f - x2;
  float den = fmaxf(1.0f + 2.0f * xy + x2 * y2, MIN_NORM);
  float inv = 1.0f / den;
  float zx = (c1 * vx + c2 * h4.x) * inv;
  float zy = (c1 * vy + c2 * h4.y) * inv;
  float zz = (c1 * vz + c2 * h4.z) * inv;
  float zw = (c1 * vw + c2 * h4.w) * inv;
  // proj
  float s3 = wave_sum(zx * zx + zy * zy + zz * zz + zw * zw);
  float n3 = fmaxf(sqrtf(s3), MIN_NORM);
  if (n3 > MAXN) { float f = MAXN / n3; zx *= f; zy *= f; zz *= f; zw *= f; }
  // logmap0
  float s4 = wave_sum(zx * zx + zy * zy + zz * zz + zw * zw);
  float n4 = fmaxf(sqrtf(s4), MIN_NORM);
  float sc = atanhf(fminf(n4, 1.0f - 1e-7f)) / n4;
  float lx = sc * zx, ly = sc * zy, lz = sc * zz, lw = sc * zw;
  ushort4 st;
  st.x = f2bf(lx); st.y = f2bf(ly); st.z = f2bf(lz); st.w = f2bf(lw);
  *(ushort4*)(L + (size_t)row * 256 + lane * 4) = st;
  // fused attention partials: head h = lane>>4, dims (lane&15)*4 ..+3
  int h = lane >> 4, db = (lane & 15) * 4;
  float4 ai = *(const float4*)(att + h * 128 + db);
  float4 aj = *(const float4*)(att + h * 128 + 64 + db);
  float di = lx * ai.x + ly * ai.y + lz * ai.z + lw * ai.w;
  float dj = lx * aj.x + ly * aj.y + lz * aj.z + lw * aj.w;
#pragma unroll
  for (int off = 1; off < 16; off <<= 1) {
    di += __shfl_xor(di, off, 64);
    dj += __shfl_xor(dj, off, 64);
  }
  if ((lane & 15) == 0) {
    s_i[row * 4 + h] = di;
    s_j[row * 4 + h] = dj;
  }
}

// ---------------- CSR buckets (ushort slots): self-loop slot 0 ----------------
__global__ void k_init(int* __restrict__ cnt, unsigned short* __restrict__ slots, int N) {
  int n = blockIdx.x * blockDim.x + threadIdx.x;
  if (n < N) { cnt[n] = 1; slots[(size_t)n * 64] = (unsigned short)n; }
}
__global__ void k_fill(const int* __restrict__ ei, int* __restrict__ cnt,
                       unsigned short* __restrict__ slots, int E) {
  int e = blockIdx.x * blockDim.x + threadIdx.x;
  if (e < E) {
    int s = ei[e];
    int d = ei[E + e];
    int pos = atomicAdd(&cnt[d], 1);
    if (pos < 64) slots[(size_t)d * 64 + pos] = (unsigned short)s;
  }
}

// ---------------- aggregation + epilogue per FINAL row i ----------------
// lane-parallel softmax (lane k scores edge k), then fma-only gather loop.
__global__ __launch_bounds__(256) void HGATLayer_49246095016355_kernel(
    const unsigned short* __restrict__ L,
    const float* __restrict__ s_i,
    const float* __restrict__ s_j,
    const int* __restrict__ cnt,
    const unsigned short* __restrict__ slots,
    const float* __restrict__ b_conv,
    float* __restrict__ out, int N) {
  int i = blockIdx.x;
  int NQ = N >> 2;
  int h = i / NQ;
  int q = i - h * NQ;
  int warp = threadIdx.x >> 6, lane = threadIdx.x & 63;
  int n = q * 4 + warp;
  int deg = min(cnt[n], 64);
  float si = s_i[n * 4 + h];
  const unsigned short* sl = slots + (size_t)n * 64;
  // parallel edge scores
  int src_l = 0;
  float a_l = -1e30f;
  if (lane < deg) {
    src_l = sl[lane];
    float t = si + s_j[src_l * 4 + h];
    a_l = (t > 0.0f) ? t : 0.2f * t;  // leaky_relu 0.2
  }
  float mx = wave_max(a_l);
  float p_l = (lane < deg) ? __expf(a_l - mx) : 0.0f;
  float sm = wave_sum(p_l);
  // share (per-wave LDS, no barrier needed: same wave writes & reads)
  __shared__ int s_src[4][64];
  __shared__ float s_w[4][64];
  s_src[warp][lane] = src_l;
  s_w[warp][lane] = p_l;
  const unsigned short* Lh = L + (size_t)h * N * 64;
  float acc0 = 0.0f, acc1 = 0.0f;
  int k = 0;
  for (; k + 1 < deg; k += 2) {
    int sA = s_src[warp][k], sB = s_src[warp][k + 1];
    float wA = s_w[warp][k], wB = s_w[warp][k + 1];
    float fA = bf2f(Lh[(size_t)sA * 64 + lane]);
    float fB = bf2f(Lh[(size_t)sB * 64 + lane]);
    acc0 = fmaf(wA, fA, acc0);
    acc1 = fmaf(wB, fB, acc1);
  }
  if (k < deg) {
    int sA = s_src[warp][k];
    float wA = s_w[warp][k];
    acc0 = fmaf(wA, bf2f(Lh[(size_t)sA * 64 + lane]), acc0);
  }
  float val = (acc0 + acc1) / fmaxf(sm, MIN_NORM);
  val += b_conv[threadIdx.x];
  val = fmaxf(val, 0.0f);  // relu
  // block-wide sumsq over this final row's 256 cols
  float ps = wave_sum(val * val);
  __shared__ float red[4];
  if (lane == 0) red[warp] = ps;
  __syncthreads();
  float tot = red[0] + red[1] + red[2] + red[3];
  float nraw = sqrtf(tot);
  float nc = fmaxf(nraw, MIN_NORM);
  float t = tanhf(nc) / nc;  // expmap0 scale
  float y = t * val;
  float ny = fmaxf(t * nraw, MIN_NORM);  // = |y|
  if (ny > MAXN) y *= MAXN / ny;         // proj
  out[(size_t)i * 256 + threadIdx.x] = y;
}

extern "C" void kernel_launch(void* const* d_in, const int* in_sizes, int n_in,
                              void* d_out, int out_size, void* d_ws, size_t ws_size,
                              hipStream_t stream) {
  const float* x   = (const float*)d_in[0];
  const int*   ei  = (const int*)d_in[1];
  const float* W   = (const float*)d_in[2];
  const float* bl  = (const float*)d_in[3];
  const float* att = (const float*)d_in[4];
  const float* bc  = (const float*)d_in[5];
  float* out = (float*)d_out;

  const int N = in_sizes[0] / 256;  // 50000
  const int E = in_sizes[1] / 2;    // 800000

  char* w = (char*)d_ws;
  // xb (bf16 x) and L (bf16 logmap) alias: xb dead before L is written
  unsigned short* LXB = (unsigned short*)w; w += (size_t)N * 256 * 2;  // 25.6 MB
  unsigned short* Wb  = (unsigned short*)w; w += 65536 * 2;            // 128 KB
  float* s_i = (float*)w; w += (size_t)N * 4 * 4;
  float* s_j = (float*)w; w += (size_t)N * 4 * 4;
  float* rs  = (float*)w; w += (size_t)N * 4;
  float* hb  = (float*)w; w += 256 * 4;
  float* hb2 = (float*)w; w += 16;
  int* cnt   = (int*)w;   w += (size_t)N * 4;
  unsigned short* slots = (unsigned short*)w;  // N*64 ushort = 6.4 MB

  k_hb<<<1, 64, 0, stream>>>(bl, hb, hb2);
  k_prep<<<N / 4, 256, 0, stream>>>(x, rs, LXB, N);
  k_wb<<<64, 256, 0, stream>>>(W, Wb);
  // V (fp32) staged in d_out, consumed by k_hyp, then overwritten by final kernel
  k_gemm<<<dim3((N + 63) / 64, 4), 256, 0, stream>>>(LXB, Wb, rs, (float*)d_out, N);
  k_hyp<<<N / 4, 256, 0, stream>>>((const float*)d_out, hb, hb2, att, LXB, s_i, s_j);
  k_init<<<(N + 255) / 256, 256, 0, stream>>>(cnt, slots, N);
  k_fill<<<(E + 255) / 256, 256, 0, stream>>>(ei, cnt, slots, E);
  HGATLayer_49246095016355_kernel<<<N, 256, 0, stream>>>(LXB, s_i, s_j, cnt, slots, bc, out, N);
}

// Round 5
// 317.757 us; speedup vs baseline: 2.0912x; 1.2136x over previous
//
#include <hip/hip_runtime.h>

#define MIN_NORM 1e-15f
#define MAXN (1.0f - 4e-3f)

typedef __attribute__((ext_vector_type(8))) short short8;   // 8 bf16 (4 VGPRs)
typedef __attribute__((ext_vector_type(4))) float f32x4;    // 4 fp32 acc

__device__ __forceinline__ float bf2f(unsigned short u) {
  union { unsigned int i; float f; } c; c.i = ((unsigned int)u) << 16; return c.f;
}
__device__ __forceinline__ unsigned short f2bf(float f) {
  union { float f; unsigned int i; } c; c.f = f;
  unsigned int r = c.i + 0x7FFFu + ((c.i >> 16) & 1u);
  return (unsigned short)(r >> 16);
}
__device__ __forceinline__ float wave_sum(float v) {
#pragma unroll
  for (int off = 32; off > 0; off >>= 1) v += __shfl_xor(v, off, 64);
  return v;
}
__device__ __forceinline__ float gsum16(float v) {  // sum over 16-lane group
#pragma unroll
  for (int off = 8; off > 0; off >>= 1) v += __shfl_xor(v, off, 64);
  return v;
}

// ---------------- hb = proj(expmap0(b_lin)), plus |hb|^2 ----------------
__global__ void k_hb(const float* __restrict__ b_lin,
                     float* __restrict__ hb, float* __restrict__ hb2) {
  int lane = threadIdx.x;  // 64 threads x 4 floats = 256
  float4 u = ((const float4*)b_lin)[lane];
  float bx = u.x, by = u.y, bz = u.z, bw = u.w;
  float s = wave_sum(bx * bx + by * by + bz * bz + bw * bw);
  float n1 = fmaxf(sqrtf(s), MIN_NORM);
  float t = tanhf(n1) / n1;
  bx *= t; by *= t; bz *= t; bw *= t;
  float s2 = wave_sum(bx * bx + by * by + bz * bz + bw * bw);
  float n2 = fmaxf(sqrtf(s2), MIN_NORM);
  if (n2 > MAXN) { float f = MAXN / n2; bx *= f; by *= f; bz *= f; bw *= f; }
  float4 o; o.x = bx; o.y = by; o.z = bz; o.w = bw;
  ((float4*)hb)[lane] = o;
  float s3 = wave_sum(bx * bx + by * by + bz * bz + bw * bw);
  if (lane == 0) *hb2 = s3;
}

// ---------------- prep: row-norm scale rs[i] (fp32) + bf16 cast of x ----------------
__global__ __launch_bounds__(256) void k_prep(const float* __restrict__ x,
                                              float* __restrict__ rs,
                                              unsigned short* __restrict__ xb, int N) {
  int row = blockIdx.x * 4 + (threadIdx.x >> 6);
  int lane = threadIdx.x & 63;
  float4 u = *(const float4*)(x + (size_t)row * 256 + lane * 4);
  ushort4 st;
  st.x = f2bf(u.x); st.y = f2bf(u.y); st.z = f2bf(u.z); st.w = f2bf(u.w);
  *(ushort4*)(xb + (size_t)row * 256 + lane * 4) = st;
  float s = wave_sum(u.x * u.x + u.y * u.y + u.z * u.z + u.w * u.w);
  if (lane == 0) {
    float n = fmaxf(sqrtf(s), MIN_NORM);
    rs[row] = atanhf(fminf(n, 1.0f - 1e-7f)) / n;
  }
}

// ---------------- W (fp32 256x256) -> bf16 ----------------
__global__ __launch_bounds__(256) void k_wb(const float* __restrict__ W,
                                            unsigned short* __restrict__ Wb) {
  int idx = (blockIdx.x * 256 + threadIdx.x) * 4;
  float4 u = *(const float4*)(W + idx);
  ushort4 st;
  st.x = f2bf(u.x); st.y = f2bf(u.y); st.z = f2bf(u.z); st.w = f2bf(u.w);
  *(ushort4*)(Wb + idx) = st;
}

// ---------------- fused MFMA GEMM + hyperbolic chain + attention partials ----------
// Block: 256 thr (4 waves), 64 Lmat rows. No LDS: B direct from L2-hot Wb (128 KB).
// Lmat row r = logmap0(proj(mobius(proj(expmap0(rs[r]*x[r]@W^T)),hb))).
// Faithful view: Lmat[r][c] = logx[h=r/12500][n=(r%12500)*4 + c/64][d=c&63].
// Stored node-major: L[n*256 + h*64 + d]. s_i/s_j[n*4+h] = logx[h][n] . att[h].
__global__ __launch_bounds__(256) void k_gemmhyp(const unsigned short* __restrict__ xb,
                                                 const unsigned short* __restrict__ Wb,
                                                 const float* __restrict__ rs,
                                                 const float* __restrict__ hb,
                                                 const float* __restrict__ hb2p,
                                                 const float* __restrict__ att,
                                                 unsigned short* __restrict__ L,
                                                 float* __restrict__ s_i,
                                                 float* __restrict__ s_j,
                                                 int M, int NQ) {
  int tid = threadIdx.x;
  int wv = tid >> 6, lane = tid & 63, qd = lane >> 4, lc = lane & 15;
  int i0 = blockIdx.x * 64;
  int arow = i0 + wv * 16 + lc;
  if (arow >= M) arow = M - 1;  // clamp; stores guarded later
  // A fragments: 8 x short8 (row arow, k = kk*32 + qd*8 .. +7)
  short8 af[8];
#pragma unroll
  for (int kk = 0; kk < 8; ++kk)
    af[kk] = *(const short8*)(xb + (size_t)arow * 256 + kk * 32 + qd * 8);
  // acc[jt]: output tile cols jt*16+lc, rows wv*16 + qd*4 + r
  f32x4 acc[16];
#pragma unroll
  for (int jt = 0; jt < 16; ++jt) acc[jt] = (f32x4){0.f, 0.f, 0.f, 0.f};
#pragma unroll
  for (int jt = 0; jt < 16; ++jt) {
    const unsigned short* wrow = Wb + (size_t)(jt * 16 + lc) * 256 + qd * 8;
#pragma unroll
    for (int kk = 0; kk < 8; ++kk) {
      short8 bf = *(const short8*)(wrow + kk * 32);
      acc[jt] = __builtin_amdgcn_mfma_f32_16x16x32_bf16(af[kk], bf, acc[jt], 0, 0, 0);
    }
  }
  // constants for the chain
  float y2 = *hb2p;
  float hbreg[16];
#pragma unroll
  for (int jt = 0; jt < 16; ++jt) hbreg[jt] = hb[jt * 16 + lc];

#pragma unroll
  for (int r = 0; r < 4; ++r) {
    int row_r = i0 + wv * 16 + qd * 4 + r;
    bool valid = row_r < M;
    int rr = valid ? row_r : M - 1;
    float rsv = rs[rr];
    float v[16];
    float ss = 0.0f;
#pragma unroll
    for (int jt = 0; jt < 16; ++jt) { v[jt] = rsv * acc[jt][r]; ss += v[jt] * v[jt]; }
    ss = gsum16(ss);
    // expmap0 + proj (analytic norms)
    float n1 = fmaxf(sqrtf(ss), MIN_NORM);
    float e1 = tanhf(n1) / n1;
    float n2 = e1 * n1;                       // |expmap0(v)|
    float f2 = (n2 > MAXN) ? MAXN / n2 : 1.0f;
    float e12 = e1 * f2;
    float nx = n2 * f2;                       // |proj(...)|
    float x2 = nx * nx;
#pragma unroll
    for (int jt = 0; jt < 16; ++jt) v[jt] *= e12;
    // mobius_add(v, hb)
    float xy = 0.0f;
#pragma unroll
    for (int jt = 0; jt < 16; ++jt) xy += v[jt] * hbreg[jt];
    xy = gsum16(xy);
    float c1 = 1.0f + 2.0f * xy + y2;
    float c2 = 1.0f - x2;
    float den = fmaxf(1.0f + 2.0f * xy + x2 * y2, MIN_NORM);
    float inv = 1.0f / den;
    // |z|^2 analytic: inv^2 (c1^2 x2 + 2 c1 c2 xy + c2^2 y2)
    float s3 = inv * inv * (c1 * c1 * x2 + 2.0f * c1 * c2 * xy + c2 * c2 * y2);
    float n3 = fmaxf(sqrtf(s3), MIN_NORM);
    float f3 = (n3 > MAXN) ? MAXN / n3 : 1.0f;
    float n4 = fmaxf(n3 * f3, MIN_NORM);      // |proj(z)| <= MAXN < 1-1e-7
    float sc = atanhf(n4) / n4;
    float g = inv * f3 * sc;
    // Lv[jt] = (c1*v + c2*hb) * g  == logmap0(proj(mobius(...)))
    float Lv[16];
#pragma unroll
    for (int jt = 0; jt < 16; ++jt) Lv[jt] = (c1 * v[jt] + c2 * hbreg[jt]) * g;
    // faithful head/node decode for this Lmat row
    int h_r = row_r / 12500;          // NQ==12500 when N=50000; general: row_r/NQ
    int q_r = row_r - h_r * NQ;
    // store node-major L: col c = jt*16+lc -> n = q_r*4 + (jt>>2), d = (jt&3)*16+lc
    if (valid) {
#pragma unroll
      for (int jt = 0; jt < 16; ++jt) {
        int n = q_r * 4 + (jt >> 2);
        int d = (jt & 3) * 16 + lc;
        L[(size_t)n * 256 + h_r * 64 + d] = f2bf(Lv[jt]);
      }
    }
    // attention partials: for g4=0..3 (node n=q_r*4+g4, head h_r)
    float pig[4], pjg[4];
#pragma unroll
    for (int g4 = 0; g4 < 4; ++g4) {
      float pi = 0.0f, pj = 0.0f;
#pragma unroll
      for (int t = 0; t < 4; ++t) {
        float a_i = att[h_r * 128 + t * 16 + lc];
        float a_j = att[h_r * 128 + 64 + t * 16 + lc];
        pi += Lv[g4 * 4 + t] * a_i;
        pj += Lv[g4 * 4 + t] * a_j;
      }
      pig[g4] = gsum16(pi);
      pjg[g4] = gsum16(pj);
    }
    if (valid && lc == 0) {
#pragma unroll
      for (int g4 = 0; g4 < 4; ++g4) {
        int n = q_r * 4 + g4;
        s_i[n * 4 + h_r] = pig[g4];
        s_j[n * 4 + h_r] = pjg[g4];
      }
    }
  }
}

// ---------------- CSR buckets (ushort slots): self-loop slot 0 ----------------
__global__ void k_init(int* __restrict__ cnt, unsigned short* __restrict__ slots, int N) {
  int n = blockIdx.x * blockDim.x + threadIdx.x;
  if (n < N) { cnt[n] = 1; slots[(size_t)n * 64] = (unsigned short)n; }
}
__global__ void k_fill(const int* __restrict__ ei, int* __restrict__ cnt,
                       unsigned short* __restrict__ slots, int E) {
  int e = blockIdx.x * blockDim.x + threadIdx.x;
  if (e < E) {
    int s = ei[e];
    int d = ei[E + e];
    int pos = atomicAdd(&cnt[d], 1);
    if (pos < 64) slots[(size_t)d * 64 + pos] = (unsigned short)s;
  }
}

// ---------------- aggregation + epilogue; block = q (4 nodes, 4 final rows) -------
// Warp w = node n=4q+w: gathers src rows (512B, all 4 heads) with per-head softmax
// weights; lane covers dims c=4*lane..+3 (head h=lane>>4, d=(lane&15)*4..+3).
__global__ __launch_bounds__(256) void HGATLayer_49246095016355_kernel(
    const unsigned short* __restrict__ L,
    const float* __restrict__ s_i,
    const float* __restrict__ s_j,
    const int* __restrict__ cnt,
    const unsigned short* __restrict__ slots,
    const float* __restrict__ b_conv,
    float* __restrict__ out, int N, int NQ) {
  int q = blockIdx.x;
  int w = threadIdx.x >> 6, lane = threadIdx.x & 63;
  int n = q * 4 + w;
  int deg = min(cnt[n], 64);
  float4 si4 = *(const float4*)(s_i + n * 4);
  // lane-parallel per-head scores for edge k=lane
  int src_l = 0;
  float4 a4 = {-1e30f, -1e30f, -1e30f, -1e30f};
  if (lane < deg) {
    src_l = slots[(size_t)n * 64 + lane];
    float4 sj4 = *(const float4*)(s_j + src_l * 4);
    float t0 = si4.x + sj4.x, t1 = si4.y + sj4.y, t2 = si4.z + sj4.z, t3 = si4.w + sj4.w;
    a4.x = (t0 > 0.f) ? t0 : 0.2f * t0;
    a4.y = (t1 > 0.f) ? t1 : 0.2f * t1;
    a4.z = (t2 > 0.f) ? t2 : 0.2f * t2;
    a4.w = (t3 > 0.f) ? t3 : 0.2f * t3;
  }
  float4 mx = a4;
#pragma unroll
  for (int off = 32; off > 0; off >>= 1) {
    mx.x = fmaxf(mx.x, __shfl_xor(mx.x, off, 64));
    mx.y = fmaxf(mx.y, __shfl_xor(mx.y, off, 64));
    mx.z = fmaxf(mx.z, __shfl_xor(mx.z, off, 64));
    mx.w = fmaxf(mx.w, __shfl_xor(mx.w, off, 64));
  }
  float4 p4 = {0.f, 0.f, 0.f, 0.f};
  if (lane < deg) {
    p4.x = __expf(a4.x - mx.x); p4.y = __expf(a4.y - mx.y);
    p4.z = __expf(a4.z - mx.z); p4.w = __expf(a4.w - mx.w);
  }
  float4 sm = p4;
#pragma unroll
  for (int off = 32; off > 0; off >>= 1) {
    sm.x += __shfl_xor(sm.x, off, 64);
    sm.y += __shfl_xor(sm.y, off, 64);
    sm.z += __shfl_xor(sm.z, off, 64);
    sm.w += __shfl_xor(sm.w, off, 64);
  }
  __shared__ int   s_src[4][64];
  __shared__ float s_w[4][64][4];
  s_src[w][lane] = src_l;
  *(float4*)&s_w[w][lane][0] = p4;  // same-wave produce/consume: no barrier needed
  int h = lane >> 4;
  float smh = (h == 0) ? sm.x : (h == 1) ? sm.y : (h == 2) ? sm.z : sm.w;
  // gather loop: 4-way unrolled, 8B/lane loads (full 512B row = all heads)
  f32x4 ac0 = {0,0,0,0}, ac1 = {0,0,0,0}, ac2 = {0,0,0,0}, ac3 = {0,0,0,0};
  int k = 0;
  for (; k + 3 < deg; k += 4) {
    int sA = s_src[w][k + 0], sB = s_src[w][k + 1];
    int sC = s_src[w][k + 2], sD = s_src[w][k + 3];
    float wA = s_w[w][k + 0][h], wB = s_w[w][k + 1][h];
    float wC = s_w[w][k + 2][h], wD = s_w[w][k + 3][h];
    ushort4 rA = *(const ushort4*)(L + (size_t)sA * 256 + lane * 4);
    ushort4 rB = *(const ushort4*)(L + (size_t)sB * 256 + lane * 4);
    ushort4 rC = *(const ushort4*)(L + (size_t)sC * 256 + lane * 4);
    ushort4 rD = *(const ushort4*)(L + (size_t)sD * 256 + lane * 4);
    ac0[0] = fmaf(wA, bf2f(rA.x), ac0[0]); ac0[1] = fmaf(wA, bf2f(rA.y), ac0[1]);
    ac0[2] = fmaf(wA, bf2f(rA.z), ac0[2]); ac0[3] = fmaf(wA, bf2f(rA.w), ac0[3]);
    ac1[0] = fmaf(wB, bf2f(rB.x), ac1[0]); ac1[1] = fmaf(wB, bf2f(rB.y), ac1[1]);
    ac1[2] = fmaf(wB, bf2f(rB.z), ac1[2]); ac1[3] = fmaf(wB, bf2f(rB.w), ac1[3]);
    ac2[0] = fmaf(wC, bf2f(rC.x), ac2[0]); ac2[1] = fmaf(wC, bf2f(rC.y), ac2[1]);
    ac2[2] = fmaf(wC, bf2f(rC.z), ac2[2]); ac2[3] = fmaf(wC, bf2f(rC.w), ac2[3]);
    ac3[0] = fmaf(wD, bf2f(rD.x), ac3[0]); ac3[1] = fmaf(wD, bf2f(rD.y), ac3[1]);
    ac3[2] = fmaf(wD, bf2f(rD.z), ac3[2]); ac3[3] = fmaf(wD, bf2f(rD.w), ac3[3]);
  }
  for (; k < deg; ++k) {
    int sA = s_src[w][k];
    float wA = s_w[w][k][h];
    ushort4 rA = *(const ushort4*)(L + (size_t)sA * 256 + lane * 4);
    ac0[0] = fmaf(wA, bf2f(rA.x), ac0[0]); ac0[1] = fmaf(wA, bf2f(rA.y), ac0[1]);
    ac0[2] = fmaf(wA, bf2f(rA.z), ac0[2]); ac0[3] = fmaf(wA, bf2f(rA.w), ac0[3]);
  }
  float isum = 1.0f / fmaxf(smh, MIN_NORM);
  float4 bc4 = *(const float4*)(b_conv + w * 64 + (lane & 15) * 4);
  float v0 = fmaxf((ac0[0] + ac1[0] + ac2[0] + ac3[0]) * isum + bc4.x, 0.0f);
  float v1 = fmaxf((ac0[1] + ac1[1] + ac2[1] + ac3[1]) * isum + bc4.y, 0.0f);
  float v2 = fmaxf((ac0[2] + ac1[2] + ac2[2] + ac3[2]) * isum + bc4.z, 0.0f);
  float v3 = fmaxf((ac0[3] + ac1[3] + ac2[3] + ac3[3]) * isum + bc4.w, 0.0f);
  // final-row (h, q) sumsq: reduce over the 16-lane group, then across warps via LDS
  float ps = v0 * v0 + v1 * v1 + v2 * v2 + v3 * v3;
  ps = gsum16(ps);
  __shared__ float red[4][4];
  if ((lane & 15) == 0) red[w][h] = ps;
  __syncthreads();
  float tot = red[0][h] + red[1][h] + red[2][h] + red[3][h];
  float nraw = sqrtf(tot);
  float nc = fmaxf(nraw, MIN_NORM);
  float t = tanhf(nc) / nc;  // expmap0 scale
  float ny = fmaxf(t * nraw, MIN_NORM);
  float f = (ny > MAXN) ? (MAXN / ny) : 1.0f;
  float tf = t * f;
  float4 y; y.x = tf * v0; y.y = tf * v1; y.z = tf * v2; y.w = tf * v3;
  *(float4*)(out + (size_t)(h * NQ + q) * 256 + w * 64 + (lane & 15) * 4) = y;
}

extern "C" void kernel_launch(void* const* d_in, const int* in_sizes, int n_in,
                              void* d_out, int out_size, void* d_ws, size_t ws_size,
                              hipStream_t stream) {
  const float* x   = (const float*)d_in[0];
  const int*   ei  = (const int*)d_in[1];
  const float* W   = (const float*)d_in[2];
  const float* bl  = (const float*)d_in[3];
  const float* att = (const float*)d_in[4];
  const float* bc  = (const float*)d_in[5];
  float* out = (float*)d_out;

  const int N = in_sizes[0] / 256;  // 50000
  const int E = in_sizes[1] / 2;    // 800000
  const int NQ = N / 4;             // 12500

  // xb (bf16 x) staged in d_out: dead before the final kernel overwrites out
  unsigned short* xb = (unsigned short*)d_out;

  char* w = (char*)d_ws;
  unsigned short* L  = (unsigned short*)w; w += (size_t)N * 256 * 2;  // 25.6 MB node-major
  unsigned short* Wb = (unsigned short*)w; w += 65536 * 2;            // 128 KB
  float* s_i = (float*)w; w += (size_t)N * 4 * 4;
  float* s_j = (float*)w; w += (size_t)N * 4 * 4;
  float* rs  = (float*)w; w += (size_t)N * 4;
  float* hb  = (float*)w; w += 256 * 4;
  float* hb2 = (float*)w; w += 16;
  int* cnt   = (int*)w;   w += (size_t)N * 4;
  unsigned short* slots = (unsigned short*)w;  // N*64 ushort = 6.4 MB

  k_hb<<<1, 64, 0, stream>>>(bl, hb, hb2);
  k_prep<<<N / 4, 256, 0, stream>>>(x, rs, xb, N);
  k_wb<<<64, 256, 0, stream>>>(W, Wb);
  k_gemmhyp<<<(N + 63) / 64, 256, 0, stream>>>(xb, Wb, rs, hb, hb2, att, L, s_i, s_j, N, NQ);
  k_init<<<(N + 255) / 256, 256, 0, stream>>>(cnt, slots, N);
  k_fill<<<(E + 255) / 256, 256, 0, stream>>>(ei, cnt, slots, E);
  HGATLayer_49246095016355_kernel<<<NQ, 256, 0, stream>>>(L, s_i, s_j, cnt, slots, bc, out, N, NQ);
}

// Round 6
// 309.646 us; speedup vs baseline: 2.1460x; 1.0262x over previous
//
#include <hip/hip_runtime.h>

#define MIN_NORM 1e-15f
#define MAXN (1.0f - 4e-3f)

typedef __attribute__((ext_vector_type(8))) short short8;   // 8 bf16 (4 VGPRs)
typedef __attribute__((ext_vector_type(4))) float f32x4;    // 4 fp32 acc

__device__ __forceinline__ float bf2f(unsigned short u) {
  union { unsigned int i; float f; } c; c.i = ((unsigned int)u) << 16; return c.f;
}
__device__ __forceinline__ unsigned short f2bf(float f) {
  union { float f; unsigned int i; } c; c.f = f;
  unsigned int r = c.i + 0x7FFFu + ((c.i >> 16) & 1u);
  return (unsigned short)(r >> 16);
}
__device__ __forceinline__ float wave_sum(float v) {
#pragma unroll
  for (int off = 32; off > 0; off >>= 1) v += __shfl_xor(v, off, 64);
  return v;
}
__device__ __forceinline__ float gsum16(float v) {  // sum over 16-lane group
#pragma unroll
  for (int off = 8; off > 0; off >>= 1) v += __shfl_xor(v, off, 64);
  return v;
}

// ---------------- prep: rs[i] + bf16 cast of x; W->bf16 (blocks<64); hb (block 64) --
__global__ __launch_bounds__(256) void k_prep(const float* __restrict__ x,
                                              const float* __restrict__ W,
                                              const float* __restrict__ b_lin,
                                              float* __restrict__ rs,
                                              unsigned short* __restrict__ xb,
                                              unsigned short* __restrict__ Wb,
                                              float* __restrict__ hb,
                                              float* __restrict__ hb2, int N) {
  int row = blockIdx.x * 4 + (threadIdx.x >> 6);
  int lane = threadIdx.x & 63;
  float4 u = *(const float4*)(x + (size_t)row * 256 + lane * 4);
  ushort4 st;
  st.x = f2bf(u.x); st.y = f2bf(u.y); st.z = f2bf(u.z); st.w = f2bf(u.w);
  *(ushort4*)(xb + (size_t)row * 256 + lane * 4) = st;
  float s = wave_sum(u.x * u.x + u.y * u.y + u.z * u.z + u.w * u.w);
  if (lane == 0) {
    float n = fmaxf(sqrtf(s), MIN_NORM);
    rs[row] = atanhf(fminf(n, 1.0f - 1e-7f)) / n;
  }
  // W -> bf16, 64 blocks x 256 thr x 4 elems = 65536
  if (blockIdx.x < 64) {
    int idx = (blockIdx.x * 256 + threadIdx.x) * 4;
    float4 wv = *(const float4*)(W + idx);
    ushort4 ws;
    ws.x = f2bf(wv.x); ws.y = f2bf(wv.y); ws.z = f2bf(wv.z); ws.w = f2bf(wv.w);
    *(ushort4*)(Wb + idx) = ws;
  }
  // hb = proj(expmap0(b_lin)) + |hb|^2, one wave
  if (blockIdx.x == 64 && threadIdx.x < 64) {
    float4 b4 = ((const float4*)b_lin)[lane];
    float bx = b4.x, by = b4.y, bz = b4.z, bw = b4.w;
    float sb = wave_sum(bx * bx + by * by + bz * bz + bw * bw);
    float n1 = fmaxf(sqrtf(sb), MIN_NORM);
    float t = tanhf(n1) / n1;
    bx *= t; by *= t; bz *= t; bw *= t;
    float s2 = wave_sum(bx * bx + by * by + bz * bz + bw * bw);
    float n2 = fmaxf(sqrtf(s2), MIN_NORM);
    if (n2 > MAXN) { float f = MAXN / n2; bx *= f; by *= f; bz *= f; bw *= f; }
    float4 o; o.x = bx; o.y = by; o.z = bz; o.w = bw;
    ((float4*)hb)[lane] = o;
    float s3 = wave_sum(bx * bx + by * by + bz * bz + bw * bw);
    if (lane == 0) *hb2 = s3;
  }
}

// ---------------- fused MFMA GEMM + hyperbolic chain + attention partials ----------
// Block: 256 thr (4 waves), 64 Lmat rows. kk-outer / jt-inner: 16 independent accs,
// B prefetched 8 frags at a time => ILP hides L2 latency on Wb reads.
__global__ __launch_bounds__(256) void k_gemmhyp(const unsigned short* __restrict__ xb,
                                                 const unsigned short* __restrict__ Wb,
                                                 const float* __restrict__ rs,
                                                 const float* __restrict__ hb,
                                                 const float* __restrict__ hb2p,
                                                 const float* __restrict__ att,
                                                 unsigned short* __restrict__ L,
                                                 float* __restrict__ s_i,
                                                 float* __restrict__ s_j,
                                                 int M, int NQ) {
  int tid = threadIdx.x;
  int wv = tid >> 6, lane = tid & 63, qd = lane >> 4, lc = lane & 15;
  int i0 = blockIdx.x * 64;
  int arow = i0 + wv * 16 + lc;
  if (arow >= M) arow = M - 1;  // clamp; stores guarded later
  short8 af[8];
#pragma unroll
  for (int kk = 0; kk < 8; ++kk)
    af[kk] = *(const short8*)(xb + (size_t)arow * 256 + kk * 32 + qd * 8);
  f32x4 acc[16];
#pragma unroll
  for (int jt = 0; jt < 16; ++jt) acc[jt] = (f32x4){0.f, 0.f, 0.f, 0.f};
#pragma unroll
  for (int kk = 0; kk < 8; ++kk) {
#pragma unroll
    for (int half = 0; half < 2; ++half) {
      short8 bf[8];
#pragma unroll
      for (int j = 0; j < 8; ++j)
        bf[j] = *(const short8*)(Wb + (size_t)((half * 8 + j) * 16 + lc) * 256 + kk * 32 + qd * 8);
#pragma unroll
      for (int j = 0; j < 8; ++j)
        acc[half * 8 + j] =
            __builtin_amdgcn_mfma_f32_16x16x32_bf16(af[kk], bf[j], acc[half * 8 + j], 0, 0, 0);
    }
  }
  // constants for the chain
  float y2 = *hb2p;
  float hbreg[16];
#pragma unroll
  for (int jt = 0; jt < 16; ++jt) hbreg[jt] = hb[jt * 16 + lc];

#pragma unroll
  for (int r = 0; r < 4; ++r) {
    int row_r = i0 + wv * 16 + qd * 4 + r;
    bool valid = row_r < M;
    int rr = valid ? row_r : M - 1;
    float rsv = rs[rr];
    float v[16];
    float ss = 0.0f;
#pragma unroll
    for (int jt = 0; jt < 16; ++jt) { v[jt] = rsv * acc[jt][r]; ss += v[jt] * v[jt]; }
    ss = gsum16(ss);
    // expmap0 + proj (analytic norms)
    float n1 = fmaxf(sqrtf(ss), MIN_NORM);
    float e1 = tanhf(n1) / n1;
    float n2 = e1 * n1;                       // |expmap0(v)|
    float f2 = (n2 > MAXN) ? MAXN / n2 : 1.0f;
    float e12 = e1 * f2;
    float nx = n2 * f2;                       // |proj(...)|
    float x2 = nx * nx;
#pragma unroll
    for (int jt = 0; jt < 16; ++jt) v[jt] *= e12;
    // mobius_add(v, hb)
    float xy = 0.0f;
#pragma unroll
    for (int jt = 0; jt < 16; ++jt) xy += v[jt] * hbreg[jt];
    xy = gsum16(xy);
    float c1 = 1.0f + 2.0f * xy + y2;
    float c2 = 1.0f - x2;
    float den = fmaxf(1.0f + 2.0f * xy + x2 * y2, MIN_NORM);
    float inv = 1.0f / den;
    float s3 = inv * inv * (c1 * c1 * x2 + 2.0f * c1 * c2 * xy + c2 * c2 * y2);
    float n3 = fmaxf(sqrtf(s3), MIN_NORM);
    float f3 = (n3 > MAXN) ? MAXN / n3 : 1.0f;
    float n4 = fmaxf(n3 * f3, MIN_NORM);      // |proj(z)| <= MAXN < 1-1e-7
    float sc = atanhf(n4) / n4;
    float g = inv * f3 * sc;
    float Lv[16];
#pragma unroll
    for (int jt = 0; jt < 16; ++jt) Lv[jt] = (c1 * v[jt] + c2 * hbreg[jt]) * g;
    // faithful head/node decode for this Lmat row
    int h_r = row_r / NQ;
    int q_r = row_r - h_r * NQ;
    if (valid) {
#pragma unroll
      for (int jt = 0; jt < 16; ++jt) {
        int n = q_r * 4 + (jt >> 2);
        int d = (jt & 3) * 16 + lc;
        L[(size_t)n * 256 + h_r * 64 + d] = f2bf(Lv[jt]);
      }
    }
    float pig[4], pjg[4];
#pragma unroll
    for (int g4 = 0; g4 < 4; ++g4) {
      float pi = 0.0f, pj = 0.0f;
#pragma unroll
      for (int t = 0; t < 4; ++t) {
        float a_i = att[h_r * 128 + t * 16 + lc];
        float a_j = att[h_r * 128 + 64 + t * 16 + lc];
        pi += Lv[g4 * 4 + t] * a_i;
        pj += Lv[g4 * 4 + t] * a_j;
      }
      pig[g4] = gsum16(pi);
      pjg[g4] = gsum16(pj);
    }
    if (valid && lc == 0) {
#pragma unroll
      for (int g4 = 0; g4 < 4; ++g4) {
        int n = q_r * 4 + g4;
        s_i[n * 4 + h_r] = pig[g4];
        s_j[n * 4 + h_r] = pjg[g4];
      }
    }
  }
}

// ---------------- CSR buckets (ushort slots): self-loop slot 0 ----------------
__global__ void k_init(int* __restrict__ cnt, unsigned short* __restrict__ slots, int N) {
  int n = blockIdx.x * blockDim.x + threadIdx.x;
  if (n < N) { cnt[n] = 1; slots[(size_t)n * 64] = (unsigned short)n; }
}
__global__ void k_fill(const int* __restrict__ ei, int* __restrict__ cnt,
                       unsigned short* __restrict__ slots, int E) {
  int e = blockIdx.x * blockDim.x + threadIdx.x;
  if (e < E) {
    int s = ei[e];
    int d = ei[E + e];
    int pos = atomicAdd(&cnt[d], 1);
    if (pos < 64) slots[(size_t)d * 64 + pos] = (unsigned short)s;
  }
}

// ---------------- aggregation + epilogue; block = q (4 nodes, 4 final rows) -------
__global__ __launch_bounds__(256) void HGATLayer_49246095016355_kernel(
    const unsigned short* __restrict__ L,
    const float* __restrict__ s_i,
    const float* __restrict__ s_j,
    const int* __restrict__ cnt,
    const unsigned short* __restrict__ slots,
    const float* __restrict__ b_conv,
    float* __restrict__ out, int N, int NQ) {
  int q = blockIdx.x;
  int w = threadIdx.x >> 6, lane = threadIdx.x & 63;
  int n = q * 4 + w;
  int deg = min(cnt[n], 64);
  float4 si4 = *(const float4*)(s_i + n * 4);
  // lane-parallel per-head scores for edge k=lane
  int src_l = 0;
  float4 a4 = {-1e30f, -1e30f, -1e30f, -1e30f};
  if (lane < deg) {
    src_l = slots[(size_t)n * 64 + lane];
    float4 sj4 = *(const float4*)(s_j + src_l * 4);
    float t0 = si4.x + sj4.x, t1 = si4.y + sj4.y, t2 = si4.z + sj4.z, t3 = si4.w + sj4.w;
    a4.x = (t0 > 0.f) ? t0 : 0.2f * t0;
    a4.y = (t1 > 0.f) ? t1 : 0.2f * t1;
    a4.z = (t2 > 0.f) ? t2 : 0.2f * t2;
    a4.w = (t3 > 0.f) ? t3 : 0.2f * t3;
  }
  float4 mx = a4;
#pragma unroll
  for (int off = 32; off > 0; off >>= 1) {
    mx.x = fmaxf(mx.x, __shfl_xor(mx.x, off, 64));
    mx.y = fmaxf(mx.y, __shfl_xor(mx.y, off, 64));
    mx.z = fmaxf(mx.z, __shfl_xor(mx.z, off, 64));
    mx.w = fmaxf(mx.w, __shfl_xor(mx.w, off, 64));
  }
  float4 p4 = {0.f, 0.f, 0.f, 0.f};
  if (lane < deg) {
    p4.x = __expf(a4.x - mx.x); p4.y = __expf(a4.y - mx.y);
    p4.z = __expf(a4.z - mx.z); p4.w = __expf(a4.w - mx.w);
  }
  float4 sm = p4;
#pragma unroll
  for (int off = 32; off > 0; off >>= 1) {
    sm.x += __shfl_xor(sm.x, off, 64);
    sm.y += __shfl_xor(sm.y, off, 64);
    sm.z += __shfl_xor(sm.z, off, 64);
    sm.w += __shfl_xor(sm.w, off, 64);
  }
  __shared__ int   s_src[4][64];
  __shared__ float s_w[4][64][4];
  s_src[w][lane] = src_l;
  *(float4*)&s_w[w][lane][0] = p4;  // same-wave produce/consume: no barrier needed
  int h = lane >> 4;
  float smh = (h == 0) ? sm.x : (h == 1) ? sm.y : (h == 2) ? sm.z : sm.w;
  // gather loop: 8-way unrolled, 8B/lane loads (full 512B row = all heads)
  f32x4 ac0 = {0,0,0,0}, ac1 = {0,0,0,0}, ac2 = {0,0,0,0}, ac3 = {0,0,0,0};
  int k = 0;
  for (; k + 7 < deg; k += 8) {
    int sA = s_src[w][k + 0], sB = s_src[w][k + 1];
    int sC = s_src[w][k + 2], sD = s_src[w][k + 3];
    int sE = s_src[w][k + 4], sF = s_src[w][k + 5];
    int sG = s_src[w][k + 6], sH = s_src[w][k + 7];
    ushort4 rA = *(const ushort4*)(L + (size_t)sA * 256 + lane * 4);
    ushort4 rB = *(const ushort4*)(L + (size_t)sB * 256 + lane * 4);
    ushort4 rC = *(const ushort4*)(L + (size_t)sC * 256 + lane * 4);
    ushort4 rD = *(const ushort4*)(L + (size_t)sD * 256 + lane * 4);
    ushort4 rE = *(const ushort4*)(L + (size_t)sE * 256 + lane * 4);
    ushort4 rF = *(const ushort4*)(L + (size_t)sF * 256 + lane * 4);
    ushort4 rG = *(const ushort4*)(L + (size_t)sG * 256 + lane * 4);
    ushort4 rH = *(const ushort4*)(L + (size_t)sH * 256 + lane * 4);
    float wA = s_w[w][k + 0][h], wB = s_w[w][k + 1][h];
    float wC = s_w[w][k + 2][h], wD = s_w[w][k + 3][h];
    float wE = s_w[w][k + 4][h], wF = s_w[w][k + 5][h];
    float wG = s_w[w][k + 6][h], wH = s_w[w][k + 7][h];
    ac0[0] = fmaf(wA, bf2f(rA.x), ac0[0]); ac0[1] = fmaf(wA, bf2f(rA.y), ac0[1]);
    ac0[2] = fmaf(wA, bf2f(rA.z), ac0[2]); ac0[3] = fmaf(wA, bf2f(rA.w), ac0[3]);
    ac1[0] = fmaf(wB, bf2f(rB.x), ac1[0]); ac1[1] = fmaf(wB, bf2f(rB.y), ac1[1]);
    ac1[2] = fmaf(wB, bf2f(rB.z), ac1[2]); ac1[3] = fmaf(wB, bf2f(rB.w), ac1[3]);
    ac2[0] = fmaf(wC, bf2f(rC.x), ac2[0]); ac2[1] = fmaf(wC, bf2f(rC.y), ac2[1]);
    ac2[2] = fmaf(wC, bf2f(rC.z), ac2[2]); ac2[3] = fmaf(wC, bf2f(rC.w), ac2[3]);
    ac3[0] = fmaf(wD, bf2f(rD.x), ac3[0]); ac3[1] = fmaf(wD, bf2f(rD.y), ac3[1]);
    ac3[2] = fmaf(wD, bf2f(rD.z), ac3[2]); ac3[3] = fmaf(wD, bf2f(rD.w), ac3[3]);
    ac0[0] = fmaf(wE, bf2f(rE.x), ac0[0]); ac0[1] = fmaf(wE, bf2f(rE.y), ac0[1]);
    ac0[2] = fmaf(wE, bf2f(rE.z), ac0[2]); ac0[3] = fmaf(wE, bf2f(rE.w), ac0[3]);
    ac1[0] = fmaf(wF, bf2f(rF.x), ac1[0]); ac1[1] = fmaf(wF, bf2f(rF.y), ac1[1]);
    ac1[2] = fmaf(wF, bf2f(rF.z), ac1[2]); ac1[3] = fmaf(wF, bf2f(rF.w), ac1[3]);
    ac2[0] = fmaf(wG, bf2f(rG.x), ac2[0]); ac2[1] = fmaf(wG, bf2f(rG.y), ac2[1]);
    ac2[2] = fmaf(wG, bf2f(rG.z), ac2[2]); ac2[3] = fmaf(wG, bf2f(rG.w), ac2[3]);
    ac3[0] = fmaf(wH, bf2f(rH.x), ac3[0]); ac3[1] = fmaf(wH, bf2f(rH.y), ac3[1]);
    ac3[2] = fmaf(wH, bf2f(rH.z), ac3[2]); ac3[3] = fmaf(wH, bf2f(rH.w), ac3[3]);
  }
  for (; k + 3 < deg; k += 4) {
    int sA = s_src[w][k + 0], sB = s_src[w][k + 1];
    int sC = s_src[w][k + 2], sD = s_src[w][k + 3];
    float wA = s_w[w][k + 0][h], wB = s_w[w][k + 1][h];
    float wC = s_w[w][k + 2][h], wD = s_w[w][k + 3][h];
    ushort4 rA = *(const ushort4*)(L + (size_t)sA * 256 + lane * 4);
    ushort4 rB = *(const ushort4*)(L + (size_t)sB * 256 + lane * 4);
    ushort4 rC = *(const ushort4*)(L + (size_t)sC * 256 + lane * 4);
    ushort4 rD = *(const ushort4*)(L + (size_t)sD * 256 + lane * 4);
    ac0[0] = fmaf(wA, bf2f(rA.x), ac0[0]); ac0[1] = fmaf(wA, bf2f(rA.y), ac0[1]);
    ac0[2] = fmaf(wA, bf2f(rA.z), ac0[2]); ac0[3] = fmaf(wA, bf2f(rA.w), ac0[3]);
    ac1[0] = fmaf(wB, bf2f(rB.x), ac1[0]); ac1[1] = fmaf(wB, bf2f(rB.y), ac1[1]);
    ac1[2] = fmaf(wB, bf2f(rB.z), ac1[2]); ac1[3] = fmaf(wB, bf2f(rB.w), ac1[3]);
    ac2[0] = fmaf(wC, bf2f(rC.x), ac2[0]); ac2[1] = fmaf(wC, bf2f(rC.y), ac2[1]);
    ac2[2] = fmaf(wC, bf2f(rC.z), ac2[2]); ac2[3] = fmaf(wC, bf2f(rC.w), ac2[3]);
    ac3[0] = fmaf(wD, bf2f(rD.x), ac3[0]); ac3[1] = fmaf(wD, bf2f(rD.y), ac3[1]);
    ac3[2] = fmaf(wD, bf2f(rD.z), ac3[2]); ac3[3] = fmaf(wD, bf2f(rD.w), ac3[3]);
  }
  for (; k < deg; ++k) {
    int sA = s_src[w][k];
    float wA = s_w[w][k][h];
    ushort4 rA = *(const ushort4*)(L + (size_t)sA * 256 + lane * 4);
    ac0[0] = fmaf(wA, bf2f(rA.x), ac0[0]); ac0[1] = fmaf(wA, bf2f(rA.y), ac0[1]);
    ac0[2] = fmaf(wA, bf2f(rA.z), ac0[2]); ac0[3] = fmaf(wA, bf2f(rA.w), ac0[3]);
  }
  float isum = 1.0f / fmaxf(smh, MIN_NORM);
  float4 bc4 = *(const float4*)(b_conv + w * 64 + (lane & 15) * 4);
  float v0 = fmaxf((ac0[0] + ac1[0] + ac2[0] + ac3[0]) * isum + bc4.x, 0.0f);
  float v1 = fmaxf((ac0[1] + ac1[1] + ac2[1] + ac3[1]) * isum + bc4.y, 0.0f);
  float v2 = fmaxf((ac0[2] + ac1[2] + ac2[2] + ac3[2]) * isum + bc4.z, 0.0f);
  float v3 = fmaxf((ac0[3] + ac1[3] + ac2[3] + ac3[3]) * isum + bc4.w, 0.0f);
  float ps = v0 * v0 + v1 * v1 + v2 * v2 + v3 * v3;
  ps = gsum16(ps);
  __shared__ float red[4][4];
  if ((lane & 15) == 0) red[w][h] = ps;
  __syncthreads();
  float tot = red[0][h] + red[1][h] + red[2][h] + red[3][h];
  float nraw = sqrtf(tot);
  float nc = fmaxf(nraw, MIN_NORM);
  float t = tanhf(nc) / nc;  // expmap0 scale
  float ny = fmaxf(t * nraw, MIN_NORM);
  float f = (ny > MAXN) ? (MAXN / ny) : 1.0f;
  float tf = t * f;
  float4 y; y.x = tf * v0; y.y = tf * v1; y.z = tf * v2; y.w = tf * v3;
  *(float4*)(out + (size_t)(h * NQ + q) * 256 + w * 64 + (lane & 15) * 4) = y;
}

extern "C" void kernel_launch(void* const* d_in, const int* in_sizes, int n_in,
                              void* d_out, int out_size, void* d_ws, size_t ws_size,
                              hipStream_t stream) {
  const float* x   = (const float*)d_in[0];
  const int*   ei  = (const int*)d_in[1];
  const float* W   = (const float*)d_in[2];
  const float* bl  = (const float*)d_in[3];
  const float* att = (const float*)d_in[4];
  const float* bc  = (const float*)d_in[5];
  float* out = (float*)d_out;

  const int N = in_sizes[0] / 256;  // 50000
  const int E = in_sizes[1] / 2;    // 800000
  const int NQ = N / 4;             // 12500

  // xb (bf16 x) staged in d_out: dead before the final kernel overwrites out
  unsigned short* xb = (unsigned short*)d_out;

  char* w = (char*)d_ws;
  unsigned short* L  = (unsigned short*)w; w += (size_t)N * 256 * 2;  // 25.6 MB node-major
  unsigned short* Wb = (unsigned short*)w; w += 65536 * 2;            // 128 KB
  float* s_i = (float*)w; w += (size_t)N * 4 * 4;
  float* s_j = (float*)w; w += (size_t)N * 4 * 4;
  float* rs  = (float*)w; w += (size_t)N * 4;
  float* hb  = (float*)w; w += 256 * 4;
  float* hb2 = (float*)w; w += 16;
  int* cnt   = (int*)w;   w += (size_t)N * 4;
  unsigned short* slots = (unsigned short*)w;  // N*64 ushort = 6.4 MB

  k_prep<<<N / 4, 256, 0, stream>>>(x, W, bl, rs, xb, Wb, hb, hb2, N);
  k_gemmhyp<<<(N + 63) / 64, 256, 0, stream>>>(xb, Wb, rs, hb, hb2, att, L, s_i, s_j, N, NQ);
  k_init<<<(N + 255) / 256, 256, 0, stream>>>(cnt, slots, N);
  k_fill<<<(E + 255) / 256, 256, 0, stream>>>(ei, cnt, slots, E);
  HGATLayer_49246095016355_kernel<<<NQ, 256, 0, stream>>>(L, s_i, s_j, cnt, slots, bc, out, N, NQ);
}